// Round 5
// baseline (1330.246 us; speedup 1.0000x reference)
//
#include <hip/hip_runtime.h>
#include <hip/hip_bf16.h>

#define HIDDEN 3072
#define INTER  8192
#define NTOK   8192   // B*S = 4*2048

typedef __attribute__((ext_vector_type(8))) short bf16x8;
typedef __attribute__((ext_vector_type(4))) float f32x4;

__device__ __forceinline__ void gload_lds16(const void* g, void* l) {
  __builtin_amdgcn_global_load_lds(
      (const __attribute__((address_space(1))) void*)g,
      (__attribute__((address_space(3))) void*)l, 16, 0, 0);
}

__device__ __forceinline__ unsigned short f2bf(float f) {
  unsigned int u = __builtin_bit_cast(unsigned int, f);
  u += 0x7fffu + ((u >> 16) & 1u);   // round-to-nearest-even
  return (unsigned short)(u >> 16);
}

// ---------------- conversion kernels ----------------

__global__ void cvt_f32_bf16(const float* __restrict__ in,
                             unsigned short* __restrict__ out, int n4) {
  int i = blockIdx.x * blockDim.x + threadIdx.x;
  if (i >= n4) return;
  float4 v = reinterpret_cast<const float4*>(in)[i];
  ushort4 o;
  o.x = f2bf(v.x); o.y = f2bf(v.y); o.z = f2bf(v.z); o.w = f2bf(v.w);
  reinterpret_cast<ushort4*>(out)[i] = o;
}

__global__ void cvt_i32_bf16(const int* __restrict__ in,
                             unsigned short* __restrict__ out, int n4) {
  int i = blockIdx.x * blockDim.x + threadIdx.x;
  if (i >= n4) return;
  int4 v = reinterpret_cast<const int4*>(in)[i];
  ushort4 o;
  o.x = f2bf((float)v.x); o.y = f2bf((float)v.y);
  o.z = f2bf((float)v.z); o.w = f2bf((float)v.w);
  reinterpret_cast<ushort4*>(out)[i] = o;
}

// W_gu convert with gate/up row interleave:
// W'-row rowp = 32*(c>>4) + 16*u + (c&15)  for h-col c, u=0 gate / 1 up.
__global__ void cvt_wgu_perm(const int* __restrict__ in,
                             unsigned short* __restrict__ out) {
  int i4 = blockIdx.x * blockDim.x + threadIdx.x;
  const int RW = HIDDEN / 4;   // 768 int4-groups per row
  if (i4 >= 2 * INTER * RW) return;
  int rowp = i4 / RW;
  int col4 = i4 - rowp * RW;
  int c = ((rowp >> 5) << 4) + (rowp & 15);
  int u = (rowp >> 4) & 1;
  int srow = u * INTER + c;
  int4 v = reinterpret_cast<const int4*>(in)[(size_t)srow * RW + col4];
  ushort4 o;
  o.x = f2bf((float)v.x); o.y = f2bf((float)v.y);
  o.z = f2bf((float)v.z); o.w = f2bf((float)v.w);
  reinterpret_cast<ushort4*>(out)[i4] = o;
}

// ---------------- 256x256 8-phase GEMM, 2-tile-deep pipeline ----------------
// C = A[M=8192][K] * B[N][K]^T, bf16 in, fp32 acc.
// 512 threads = 8 waves (2M x 4N). Per wave: 128x64 output = acc[8][4] f32x4.
// LDS: [parity][op A/B][k-half][256 rows][32 cols] bf16 = 128 KiB.
//
// DEEP-PIPELINE stage schedule (round-5): each buffer is free one phase
// after its last read, so tile t issues stages for t+2 (same parity as t;
// write-after-read safe via the phase-end barriers):
//   P1 -> B(t+1)kh1   P2 -> A(t+2)kh0   P3 -> B(t+2)kh0   P4 -> A(t+2)kh1
// Issue->consume distance: 5-7 phases (>= ~900cy HBM latency).
//
// vmcnt ledger (2 loads/stage, per-wave, chronological issue order
// ... A(t+1)k1@t-1:P4, B(t+1)k1@t:P1, A(t+2)k0@t:P2, B(t+2)k0@t:P3, A(t+2)k1@t:P4 ...):
//   W1 (end of t-1:P4, before t:P1 reads kh0): need B(t)k0 [t-2:P3];
//     after it: A(t)k1, B(t)k1, A(t+1)k0, B(t+1)k0, A(t+1)k1 = 5 stages
//     -> vmcnt(10); tail: entering t=NT-1 -> vmcnt(4).
//   W2 (end of t:P2, before P3 reads kh1): need B(t)k1 [t-1:P1];
//     after it: A(t+1)k0, B(t+1)k0, A(t+1)k1, B(t+1)k1, A(t+2)k0 = 5 stages
//     -> vmcnt(10); tail: t=NT-2 -> vmcnt(8); t=NT-1 -> vmcnt(0).
// Prologue: 7 stages (A0k0,B0k0,A0k1,B0k1,A1k0,B1k0,A1k1); after B0k0
// there are 5 stages = vmcnt(10). t=0:P1 issues B1k1, continuing the pattern.

template<int K, int N, bool SWIGLU>
__global__ __launch_bounds__(512, 2) void gemm8p(
    const unsigned short* __restrict__ A,   // [NTOK][K]
    const unsigned short* __restrict__ B,   // [N][K]
    const float* __restrict__ scale,
    void* __restrict__ outv)
{
  constexpr int NT = K / 64;
  __shared__ __align__(16) unsigned short lds[2][2][2][256 * 32];

  const int nbn = N / 256;
  const int nwg = (NTOK / 256) * nbn;       // %8 == 0 for both instantiations
  int bid = blockIdx.x;
  int wg = (bid & 7) * (nwg >> 3) + (bid >> 3);   // XCD-aware bijective swizzle
  const int bm = (wg / nbn) * 256;
  const int bn = (wg % nbn) * 256;

  const int tid  = threadIdx.x;
  const int lane = tid & 63;
  const int wid  = tid >> 6;
  const int wr = wid >> 2;                  // 0..1
  const int wc = wid & 3;                   // 0..3

  // staging coords: chunk = inst*512 + tid; row = chunk>>2, cb = chunk&3
  const int srow0 = tid >> 2;               // rows 0..127 (inst 0)
  const int srow1 = 128 + (tid >> 2);       // rows 128..255 (inst 1)
  const int scb   = tid & 3;

  const unsigned short* Ab = A + (size_t)bm * K;
  const unsigned short* Bb = B + (size_t)bn * K;

  auto stage = [&](const unsigned short* Gb, int op, int tt, int kh) {
    if (tt >= NT) return;
    int p = tt & 1;
    int kc = tt * 64 + kh * 32;
    unsigned short* lbase = &lds[p][op][kh][0];
    gload_lds16(Gb + (size_t)srow0 * K + kc + ((scb ^ (srow0 & 3)) * 8),
                lbase + (size_t)tid * 8);
    gload_lds16(Gb + (size_t)srow1 * K + kc + ((scb ^ (srow1 & 3)) * 8),
                lbase + (size_t)(512 + tid) * 8);
  };

  auto readA = [&](int p, int kh, int m) -> bf16x8 {
    int row = wr * 128 + m * 16 + (lane & 15);
    int cb = (lane >> 4) ^ (row & 3);
    return *(const bf16x8*)&lds[p][0][kh][row * 32 + cb * 8];
  };
  auto readB = [&](int p, int kh, int n) -> bf16x8 {
    int row = wc * 64 + n * 16 + (lane & 15);
    int cb = (lane >> 4) ^ (row & 3);
    return *(const bf16x8*)&lds[p][1][kh][row * 32 + cb * 8];
  };

  f32x4 acc[8][4] = {};
  bf16x8 af[8];

  // prologue: tile 0 fully + tile 1 minus B(1)kh1 (issued at t=0 P1)
  stage(Ab, 0, 0, 0);
  stage(Bb, 1, 0, 0);
  stage(Ab, 0, 0, 1);
  stage(Bb, 1, 0, 1);
  stage(Ab, 0, 1, 0);
  stage(Bb, 1, 1, 0);
  stage(Ab, 0, 1, 1);
  asm volatile("s_waitcnt vmcnt(10)" ::: "memory");
  __builtin_amdgcn_s_barrier();

  for (int t = 0; t < NT; ++t) {
    const int pr = t & 1;
    // ---- phase 1: kh0, n-frags 0,1 ----
#pragma unroll
    for (int m = 0; m < 8; ++m) af[m] = readA(pr, 0, m);
    bf16x8 b0 = readB(pr, 0, 0);
    bf16x8 b1 = readB(pr, 0, 1);
    stage(Bb, 1, t + 1, 1);
    __builtin_amdgcn_s_barrier();
    __builtin_amdgcn_s_setprio(1);
#pragma unroll
    for (int m = 0; m < 8; ++m) {
      acc[m][0] = __builtin_amdgcn_mfma_f32_16x16x32_bf16(af[m], b0, acc[m][0], 0, 0, 0);
      acc[m][1] = __builtin_amdgcn_mfma_f32_16x16x32_bf16(af[m], b1, acc[m][1], 0, 0, 0);
    }
    __builtin_amdgcn_s_setprio(0);
    __builtin_amdgcn_s_barrier();

    // ---- phase 2: kh0, n-frags 2,3 ----
    b0 = readB(pr, 0, 2);
    b1 = readB(pr, 0, 3);
    stage(Ab, 0, t + 2, 0);
    __builtin_amdgcn_s_barrier();
    __builtin_amdgcn_s_setprio(1);
#pragma unroll
    for (int m = 0; m < 8; ++m) {
      acc[m][2] = __builtin_amdgcn_mfma_f32_16x16x32_bf16(af[m], b0, acc[m][2], 0, 0, 0);
      acc[m][3] = __builtin_amdgcn_mfma_f32_16x16x32_bf16(af[m], b1, acc[m][3], 0, 0, 0);
    }
    __builtin_amdgcn_s_setprio(0);
    // W2: need this tile's kh1 landed before P3 (tail-exact per ledger)
    if (t + 2 < NT) {
      asm volatile("s_waitcnt vmcnt(10)" ::: "memory");
    } else if (t + 1 < NT) {
      asm volatile("s_waitcnt vmcnt(8)" ::: "memory");
    } else {
      asm volatile("s_waitcnt vmcnt(0)" ::: "memory");
    }
    __builtin_amdgcn_s_barrier();

    // ---- phase 3: kh1, n-frags 0,1 ----
#pragma unroll
    for (int m = 0; m < 8; ++m) af[m] = readA(pr, 1, m);
    b0 = readB(pr, 1, 0);
    b1 = readB(pr, 1, 1);
    stage(Bb, 1, t + 2, 0);
    __builtin_amdgcn_s_barrier();
    __builtin_amdgcn_s_setprio(1);
#pragma unroll
    for (int m = 0; m < 8; ++m) {
      acc[m][0] = __builtin_amdgcn_mfma_f32_16x16x32_bf16(af[m], b0, acc[m][0], 0, 0, 0);
      acc[m][1] = __builtin_amdgcn_mfma_f32_16x16x32_bf16(af[m], b1, acc[m][1], 0, 0, 0);
    }
    __builtin_amdgcn_s_setprio(0);
    __builtin_amdgcn_s_barrier();

    // ---- phase 4: kh1, n-frags 2,3 ----
    b0 = readB(pr, 1, 2);
    b1 = readB(pr, 1, 3);
    stage(Ab, 0, t + 2, 1);
    __builtin_amdgcn_s_barrier();
    __builtin_amdgcn_s_setprio(1);
#pragma unroll
    for (int m = 0; m < 8; ++m) {
      acc[m][2] = __builtin_amdgcn_mfma_f32_16x16x32_bf16(af[m], b0, acc[m][2], 0, 0, 0);
      acc[m][3] = __builtin_amdgcn_mfma_f32_16x16x32_bf16(af[m], b1, acc[m][3], 0, 0, 0);
    }
    __builtin_amdgcn_s_setprio(0);
    // W1: next tile's kh0 must be landed before its P1 reads (tail-exact)
    if (t + 2 < NT) {
      asm volatile("s_waitcnt vmcnt(10)" ::: "memory");
    } else if (t + 1 < NT) {
      asm volatile("s_waitcnt vmcnt(4)" ::: "memory");
    } else {
      asm volatile("s_waitcnt vmcnt(0)" ::: "memory");
    }
    __builtin_amdgcn_s_barrier();
  }

  // ---- epilogue: C/D layout col=lane&15, row=(lane>>4)*4+j ----
  const int crow0 = (lane >> 4) * 4;
  const int ccol  = lane & 15;
  if constexpr (SWIGLU) {
    unsigned short* H = (unsigned short*)outv;     // [NTOK][INTER]
    const int hbase = (bn >> 1) + wc * 32;
#pragma unroll
    for (int np = 0; np < 2; ++np) {
      int hcol = hbase + np * 16 + ccol;
      float sg = scale[hcol];
      float su = scale[INTER + hcol];
#pragma unroll
      for (int m = 0; m < 8; ++m) {
#pragma unroll
        for (int j = 0; j < 4; ++j) {
          int row = bm + wr * 128 + m * 16 + crow0 + j;
          float g = acc[m][2 * np + 0][j] * sg;
          float u = acc[m][2 * np + 1][j] * su;
          float s = g / (1.0f + __expf(-g));       // silu
          H[(size_t)row * INTER + hcol] = f2bf(u * s);
        }
      }
    }
  } else {
    float* O = (float*)outv;                       // [NTOK][N]
#pragma unroll
    for (int n = 0; n < 4; ++n) {
      int col = bn + wc * 64 + n * 16 + ccol;
      float sc = scale[col];
#pragma unroll
      for (int m = 0; m < 8; ++m) {
#pragma unroll
        for (int j = 0; j < 4; ++j) {
          int row = bm + wr * 128 + m * 16 + crow0 + j;
          O[(size_t)row * N + col] = acc[m][n][j] * sc;
        }
      }
    }
  }
}

// ---------------- launch ----------------

extern "C" void kernel_launch(void* const* d_in, const int* in_sizes, int n_in,
                              void* d_out, int out_size, void* d_ws, size_t ws_size,
                              hipStream_t stream) {
  (void)in_sizes; (void)n_in; (void)out_size; (void)ws_size;

  const float* hidden = (const float*)d_in[0];   // [NTOK][HIDDEN] f32
  const int*   guq    = (const int*)d_in[1];     // [2*INTER][HIDDEN] i32
  const float* gus    = (const float*)d_in[2];   // [2*INTER]
  const int*   dwq    = (const int*)d_in[3];     // [HIDDEN][INTER] i32
  const float* dsc    = (const float*)d_in[4];   // [HIDDEN]
  float* out = (float*)d_out;

  char* ws = (char*)d_ws;
  unsigned short* xb  = (unsigned short*)(ws);                      // 50,331,648 B
  unsigned short* wgu = (unsigned short*)(ws + 50331648ull);        // 100,663,296 B (permuted)
  unsigned short* wd  = (unsigned short*)(ws + 150994944ull);       // 50,331,648 B
  unsigned short* hb  = (unsigned short*)(ws + 201326592ull);       // 134,217,728 B
  // total ws use: 335,544,320 B

  {
    int n4 = NTOK * HIDDEN / 4;
    cvt_f32_bf16<<<(n4 + 255) / 256, 256, 0, stream>>>(hidden, xb, n4);
  }
  {
    int n4 = 2 * INTER * HIDDEN / 4;
    cvt_wgu_perm<<<(n4 + 255) / 256, 256, 0, stream>>>(guq, wgu);
  }
  {
    int n4 = HIDDEN * INTER / 4;
    cvt_i32_bf16<<<(n4 + 255) / 256, 256, 0, stream>>>(dwq, wd, n4);
  }

  // GEMM1+SwiGLU: [8192 x 16384] over K=3072, writes H bf16 [8192][8192]
  gemm8p<HIDDEN, 2 * INTER, true>
      <<<(NTOK / 256) * (2 * INTER / 256), 512, 0, stream>>>(xb, wgu, gus, hb);
  // GEMM2: [8192 x 3072] over K=8192, writes out f32
  gemm8p<INTER, HIDDEN, false>
      <<<(NTOK / 256) * (HIDDEN / 256), 512, 0, stream>>>(hb, wd, dsc, out);
}

// Round 6
// 1266.574 us; speedup vs baseline: 1.0503x; 1.0503x over previous
//
#include <hip/hip_runtime.h>
#include <hip/hip_bf16.h>

#define HIDDEN 3072
#define INTER  8192
#define NTOK   8192   // B*S = 4*2048

typedef __attribute__((ext_vector_type(8))) short bf16x8;
typedef __attribute__((ext_vector_type(4))) float f32x4;

__device__ __forceinline__ void gload_lds16(const void* g, void* l) {
  __builtin_amdgcn_global_load_lds(
      (const __attribute__((address_space(1))) void*)g,
      (__attribute__((address_space(3))) void*)l, 16, 0, 0);
}

__device__ __forceinline__ unsigned short f2bf(float f) {
  unsigned int u = __builtin_bit_cast(unsigned int, f);
  u += 0x7fffu + ((u >> 16) & 1u);   // round-to-nearest-even
  return (unsigned short)(u >> 16);
}

// ---------------- conversion kernels ----------------

__global__ void cvt_f32_bf16(const float* __restrict__ in,
                             unsigned short* __restrict__ out, int n4) {
  int i = blockIdx.x * blockDim.x + threadIdx.x;
  if (i >= n4) return;
  float4 v = reinterpret_cast<const float4*>(in)[i];
  ushort4 o;
  o.x = f2bf(v.x); o.y = f2bf(v.y); o.z = f2bf(v.z); o.w = f2bf(v.w);
  reinterpret_cast<ushort4*>(out)[i] = o;
}

__global__ void cvt_i32_bf16(const int* __restrict__ in,
                             unsigned short* __restrict__ out, int n4) {
  int i = blockIdx.x * blockDim.x + threadIdx.x;
  if (i >= n4) return;
  int4 v = reinterpret_cast<const int4*>(in)[i];
  ushort4 o;
  o.x = f2bf((float)v.x); o.y = f2bf((float)v.y);
  o.z = f2bf((float)v.z); o.w = f2bf((float)v.w);
  reinterpret_cast<ushort4*>(out)[i] = o;
}

// W_gu convert with gate/up row interleave:
// W'-row rowp = 32*(c>>4) + 16*u + (c&15)  for h-col c, u=0 gate / 1 up.
__global__ void cvt_wgu_perm(const int* __restrict__ in,
                             unsigned short* __restrict__ out) {
  int i4 = blockIdx.x * blockDim.x + threadIdx.x;
  const int RW = HIDDEN / 4;   // 768 int4-groups per row
  if (i4 >= 2 * INTER * RW) return;
  int rowp = i4 / RW;
  int col4 = i4 - rowp * RW;
  int c = ((rowp >> 5) << 4) + (rowp & 15);
  int u = (rowp >> 4) & 1;
  int srow = u * INTER + c;
  int4 v = reinterpret_cast<const int4*>(in)[(size_t)srow * RW + col4];
  ushort4 o;
  o.x = f2bf((float)v.x); o.y = f2bf((float)v.y);
  o.z = f2bf((float)v.z); o.w = f2bf((float)v.w);
  reinterpret_cast<ushort4*>(out)[i4] = o;
}

// ---------------- 256x256 8-phase GEMM, 2-tile-deep pipeline ----------------
// C = A[M=8192][K] * B[N][K]^T, bf16 in, fp32 acc.
// 512 threads = 8 waves (2M x 4N). Per wave: 128x64 output = acc[8][4] f32x4.
// LDS: [parity][op A/B][k-half][256 rows][32 cols] bf16 = 128 KiB.
//
// SWIZZLE (round-6 fix): chunk swizzle s(row) = (row>>1)&3 (was row&3).
// Bank-quad of a 16B chunk = (4*(row&1) + c_l) mod 8. With c_l = g ^ s(row),
// a 16-lane fragment read (rows base..base+15, base%16==0) hits each of the
// 8 bank-quads exactly TWICE -> 2-way aliasing = free (m136). The old row&3
// put rows {0,4,8,12} on ONE quad -> 4-way conflict (counted: 4 cy/read,
// SQ_LDS_BANK_CONFLICT=7.55e7). Involution on both sides: staging reads
// global chunk (scb ^ s(row)) into linear LDS chunk scb; fragment read takes
// LDS chunk (g ^ s(row)). LDS[r][c] = G[r][c^s(r)]; read c=j^s(r) -> G[r][j].
//
// Stage schedule (validated round-5): tile t issues
//   P1 -> B(t+1)kh1   P2 -> A(t+2)kh0   P3 -> B(t+2)kh0   P4 -> A(t+2)kh1
// vmcnt ledger identical to round-5 (W1/W2 = 10 steady; tails 8/4/0).

template<int K, int N, bool SWIGLU>
__global__ __launch_bounds__(512, 2) void gemm8p(
    const unsigned short* __restrict__ A,   // [NTOK][K]
    const unsigned short* __restrict__ B,   // [N][K]
    const float* __restrict__ scale,
    void* __restrict__ outv)
{
  constexpr int NT = K / 64;
  __shared__ __align__(16) unsigned short lds[2][2][2][256 * 32];

  const int nbn = N / 256;
  const int nwg = (NTOK / 256) * nbn;       // %8 == 0 for both instantiations
  int bid = blockIdx.x;
  int wg = (bid & 7) * (nwg >> 3) + (bid >> 3);   // XCD-aware bijective swizzle
  const int bm = (wg / nbn) * 256;
  const int bn = (wg % nbn) * 256;

  const int tid  = threadIdx.x;
  const int lane = tid & 63;
  const int wid  = tid >> 6;
  const int wr = wid >> 2;                  // 0..1
  const int wc = wid & 3;                   // 0..3

  // staging coords: chunk = inst*512 + tid; row = chunk>>2, c_l = chunk&3
  const int srow0 = tid >> 2;               // rows 0..127 (inst 0)
  const int srow1 = 128 + (tid >> 2);       // rows 128..255 (inst 1)
  const int scb   = tid & 3;

  const unsigned short* Ab = A + (size_t)bm * K;
  const unsigned short* Bb = B + (size_t)bn * K;

  auto stage = [&](const unsigned short* Gb, int op, int tt, int kh) {
    if (tt >= NT) return;
    int p = tt & 1;
    int kc = tt * 64 + kh * 32;
    unsigned short* lbase = &lds[p][op][kh][0];
    gload_lds16(Gb + (size_t)srow0 * K + kc + ((scb ^ ((srow0 >> 1) & 3)) * 8),
                lbase + (size_t)tid * 8);
    gload_lds16(Gb + (size_t)srow1 * K + kc + ((scb ^ ((srow1 >> 1) & 3)) * 8),
                lbase + (size_t)(512 + tid) * 8);
  };

  auto readA = [&](int p, int kh, int m) -> bf16x8 {
    int row = wr * 128 + m * 16 + (lane & 15);
    int cb = (lane >> 4) ^ ((row >> 1) & 3);
    return *(const bf16x8*)&lds[p][0][kh][row * 32 + cb * 8];
  };
  auto readB = [&](int p, int kh, int n) -> bf16x8 {
    int row = wc * 64 + n * 16 + (lane & 15);
    int cb = (lane >> 4) ^ ((row >> 1) & 3);
    return *(const bf16x8*)&lds[p][1][kh][row * 32 + cb * 8];
  };

  f32x4 acc[8][4] = {};
  bf16x8 af[8];

  // prologue: tile 0 fully + tile 1 minus B(1)kh1 (issued at t=0 P1)
  stage(Ab, 0, 0, 0);
  stage(Bb, 1, 0, 0);
  stage(Ab, 0, 0, 1);
  stage(Bb, 1, 0, 1);
  stage(Ab, 0, 1, 0);
  stage(Bb, 1, 1, 0);
  stage(Ab, 0, 1, 1);
  asm volatile("s_waitcnt vmcnt(10)" ::: "memory");
  __builtin_amdgcn_s_barrier();

  for (int t = 0; t < NT; ++t) {
    const int pr = t & 1;
    // ---- phase 1: kh0, n-frags 0,1 ----
#pragma unroll
    for (int m = 0; m < 8; ++m) af[m] = readA(pr, 0, m);
    bf16x8 b0 = readB(pr, 0, 0);
    bf16x8 b1 = readB(pr, 0, 1);
    stage(Bb, 1, t + 1, 1);
    __builtin_amdgcn_s_barrier();
    __builtin_amdgcn_s_setprio(1);
#pragma unroll
    for (int m = 0; m < 8; ++m) {
      acc[m][0] = __builtin_amdgcn_mfma_f32_16x16x32_bf16(af[m], b0, acc[m][0], 0, 0, 0);
      acc[m][1] = __builtin_amdgcn_mfma_f32_16x16x32_bf16(af[m], b1, acc[m][1], 0, 0, 0);
    }
    __builtin_amdgcn_s_setprio(0);
    __builtin_amdgcn_s_barrier();

    // ---- phase 2: kh0, n-frags 2,3 ----
    b0 = readB(pr, 0, 2);
    b1 = readB(pr, 0, 3);
    stage(Ab, 0, t + 2, 0);
    __builtin_amdgcn_s_barrier();
    __builtin_amdgcn_s_setprio(1);
#pragma unroll
    for (int m = 0; m < 8; ++m) {
      acc[m][2] = __builtin_amdgcn_mfma_f32_16x16x32_bf16(af[m], b0, acc[m][2], 0, 0, 0);
      acc[m][3] = __builtin_amdgcn_mfma_f32_16x16x32_bf16(af[m], b1, acc[m][3], 0, 0, 0);
    }
    __builtin_amdgcn_s_setprio(0);
    // W2: need this tile's kh1 landed before P3 (tail-exact per ledger)
    if (t + 2 < NT) {
      asm volatile("s_waitcnt vmcnt(10)" ::: "memory");
    } else if (t + 1 < NT) {
      asm volatile("s_waitcnt vmcnt(8)" ::: "memory");
    } else {
      asm volatile("s_waitcnt vmcnt(0)" ::: "memory");
    }
    __builtin_amdgcn_s_barrier();

    // ---- phase 3: kh1, n-frags 0,1 ----
#pragma unroll
    for (int m = 0; m < 8; ++m) af[m] = readA(pr, 1, m);
    b0 = readB(pr, 1, 0);
    b1 = readB(pr, 1, 1);
    stage(Bb, 1, t + 2, 0);
    __builtin_amdgcn_s_barrier();
    __builtin_amdgcn_s_setprio(1);
#pragma unroll
    for (int m = 0; m < 8; ++m) {
      acc[m][0] = __builtin_amdgcn_mfma_f32_16x16x32_bf16(af[m], b0, acc[m][0], 0, 0, 0);
      acc[m][1] = __builtin_amdgcn_mfma_f32_16x16x32_bf16(af[m], b1, acc[m][1], 0, 0, 0);
    }
    __builtin_amdgcn_s_setprio(0);
    __builtin_amdgcn_s_barrier();

    // ---- phase 4: kh1, n-frags 2,3 ----
    b0 = readB(pr, 1, 2);
    b1 = readB(pr, 1, 3);
    stage(Ab, 0, t + 2, 1);
    __builtin_amdgcn_s_barrier();
    __builtin_amdgcn_s_setprio(1);
#pragma unroll
    for (int m = 0; m < 8; ++m) {
      acc[m][2] = __builtin_amdgcn_mfma_f32_16x16x32_bf16(af[m], b0, acc[m][2], 0, 0, 0);
      acc[m][3] = __builtin_amdgcn_mfma_f32_16x16x32_bf16(af[m], b1, acc[m][3], 0, 0, 0);
    }
    __builtin_amdgcn_s_setprio(0);
    // W1: next tile's kh0 must be landed before its P1 reads (tail-exact)
    if (t + 2 < NT) {
      asm volatile("s_waitcnt vmcnt(10)" ::: "memory");
    } else if (t + 1 < NT) {
      asm volatile("s_waitcnt vmcnt(4)" ::: "memory");
    } else {
      asm volatile("s_waitcnt vmcnt(0)" ::: "memory");
    }
    __builtin_amdgcn_s_barrier();
  }

  // ---- epilogue: C/D layout col=lane&15, row=(lane>>4)*4+j ----
  const int crow0 = (lane >> 4) * 4;
  const int ccol  = lane & 15;
  if constexpr (SWIGLU) {
    unsigned short* H = (unsigned short*)outv;     // [NTOK][INTER]
    const int hbase = (bn >> 1) + wc * 32;
#pragma unroll
    for (int np = 0; np < 2; ++np) {
      int hcol = hbase + np * 16 + ccol;
      float sg = scale[hcol];
      float su = scale[INTER + hcol];
#pragma unroll
      for (int m = 0; m < 8; ++m) {
#pragma unroll
        for (int j = 0; j < 4; ++j) {
          int row = bm + wr * 128 + m * 16 + crow0 + j;
          float g = acc[m][2 * np + 0][j] * sg;
          float u = acc[m][2 * np + 1][j] * su;
          float s = g / (1.0f + __expf(-g));       // silu
          H[(size_t)row * INTER + hcol] = f2bf(u * s);
        }
      }
    }
  } else {
    float* O = (float*)outv;                       // [NTOK][N]
#pragma unroll
    for (int n = 0; n < 4; ++n) {
      int col = bn + wc * 64 + n * 16 + ccol;
      float sc = scale[col];
#pragma unroll
      for (int m = 0; m < 8; ++m) {
#pragma unroll
        for (int j = 0; j < 4; ++j) {
          int row = bm + wr * 128 + m * 16 + crow0 + j;
          O[(size_t)row * N + col] = acc[m][n][j] * sc;
        }
      }
    }
  }
}

// ---------------- launch ----------------

extern "C" void kernel_launch(void* const* d_in, const int* in_sizes, int n_in,
                              void* d_out, int out_size, void* d_ws, size_t ws_size,
                              hipStream_t stream) {
  (void)in_sizes; (void)n_in; (void)out_size; (void)ws_size;

  const float* hidden = (const float*)d_in[0];   // [NTOK][HIDDEN] f32
  const int*   guq    = (const int*)d_in[1];     // [2*INTER][HIDDEN] i32
  const float* gus    = (const float*)d_in[2];   // [2*INTER]
  const int*   dwq    = (const int*)d_in[3];     // [HIDDEN][INTER] i32
  const float* dsc    = (const float*)d_in[4];   // [HIDDEN]
  float* out = (float*)d_out;

  char* ws = (char*)d_ws;
  unsigned short* xb  = (unsigned short*)(ws);                      // 50,331,648 B
  unsigned short* wgu = (unsigned short*)(ws + 50331648ull);        // 100,663,296 B (permuted)
  unsigned short* wd  = (unsigned short*)(ws + 150994944ull);       // 50,331,648 B
  unsigned short* hb  = (unsigned short*)(ws + 201326592ull);       // 134,217,728 B
  // total ws use: 335,544,320 B

  {
    int n4 = NTOK * HIDDEN / 4;
    cvt_f32_bf16<<<(n4 + 255) / 256, 256, 0, stream>>>(hidden, xb, n4);
  }
  {
    int n4 = 2 * INTER * HIDDEN / 4;
    cvt_wgu_perm<<<(n4 + 255) / 256, 256, 0, stream>>>(guq, wgu);
  }
  {
    int n4 = HIDDEN * INTER / 4;
    cvt_i32_bf16<<<(n4 + 255) / 256, 256, 0, stream>>>(dwq, wd, n4);
  }

  // GEMM1+SwiGLU: [8192 x 16384] over K=3072, writes H bf16 [8192][8192]
  gemm8p<HIDDEN, 2 * INTER, true>
      <<<(NTOK / 256) * (2 * INTER / 256), 512, 0, stream>>>(xb, wgu, gus, hb);
  // GEMM2: [8192 x 3072] over K=8192, writes out f32
  gemm8p<INTER, HIDDEN, false>
      <<<(NTOK / 256) * (HIDDEN / 256), 512, 0, stream>>>(hb, wd, dsc, out);
}